// Round 1
// baseline (651.289 us; speedup 1.0000x reference)
//
#include <hip/hip_runtime.h>
#include <math.h>

#define BIGV 10000000.0f
#define NB   64
#define TFULL 1024
#define TSD   1022
#define NBINS 64

// ---------------- shared memory layouts (union, <64KB) ----------------
struct SmemDtw {
  float ys[1024];
  float buf[3][1026];
};
struct SmemFused {
  float xr[1024], yr[1024];
  float fmp[5 * 1024], fmt[5 * 1024];   // also aliased for sdx/sdy before wavelet
  float aA[512], aB[512];
  float part[2048];
  float hx[NBINS], hy[NBINS];
  float red[16];
  float energy[8];
};
union SmemU { SmemDtw d; SmemFused f; };

// ---------------- reductions ----------------
__device__ __forceinline__ float waveReduceSum(float v) {
#pragma unroll
  for (int o = 32; o > 0; o >>= 1) v += __shfl_xor(v, o, 64);
  return v;
}

template <int OP>  // 0=sum 1=min 2=max
__device__ __forceinline__ float comb2(float a, float b) {
  if (OP == 0) return a + b;
  if (OP == 1) return fminf(a, b);
  return fmaxf(a, b);
}

template <int OP>
__device__ float blockReduce(float v, float* red, int tid) {
#pragma unroll
  for (int o = 32; o > 0; o >>= 1) v = comb2<OP>(v, __shfl_xor(v, o, 64));
  __syncthreads();                    // protect red from previous use
  if ((tid & 63) == 0) red[tid >> 6] = v;
  __syncthreads();
  if (tid == 0) {
    float r = red[0];
#pragma unroll
    for (int w = 1; w < 16; ++w) r = comb2<OP>(r, red[w]);
    red[0] = r;
  }
  __syncthreads();
  return red[0];
}

// ---------------- cdf_variance partial (per batch row) ----------------
__device__ float cdf_pair(const float* X, const float* Y, int N, SmemFused& s, int tid) {
  float xlo = 3.4e38f, xhi = -3.4e38f, ylo = 3.4e38f, yhi = -3.4e38f;
  for (int i = tid; i < N; i += 1024) {
    float xv = X[i], yv = Y[i];
    xlo = fminf(xlo, xv); xhi = fmaxf(xhi, xv);
    ylo = fminf(ylo, yv); yhi = fmaxf(yhi, yv);
  }
  xlo = blockReduce<1>(xlo, s.red, tid);
  xhi = blockReduce<2>(xhi, s.red, tid);
  ylo = blockReduce<1>(ylo, s.red, tid);
  yhi = blockReduce<2>(yhi, s.red, tid);
  float xinv = 1.f / (xhi - xlo + 1e-6f);
  float yinv = 1.f / (yhi - ylo + 1e-6f);

  int bin = tid >> 4, sub = tid & 15;
  float c = (float)bin * (1.f / 63.f);
  float hxp = 0.f, hyp = 0.f;
  for (int i = sub; i < N; i += 16) {
    float dx = (X[i] - xlo) * xinv - c;
    float dy = (Y[i] - ylo) * yinv - c;
    hxp += __expf(-200.f * dx * dx);   // exp(-0.5*(d/0.05)^2)
    hyp += __expf(-200.f * dy * dy);
  }
  s.part[tid] = hxp;
  s.part[1024 + tid] = hyp;
  __syncthreads();
  if (tid < NBINS) {
    float hx = 1e-6f, hy = 1e-6f;
#pragma unroll
    for (int t = 0; t < 16; ++t) {
      hx += s.part[tid * 16 + t];
      hy += s.part[1024 + tid * 16 + t];
    }
    s.hx[tid] = hx; s.hy[tid] = hy;
  }
  __syncthreads();
  if (tid == 0) {
    float totx = 0.f, toty = 0.f;
    for (int b2 = 0; b2 < NBINS; ++b2) { totx += s.hx[b2]; toty += s.hy[b2]; }
    float ix = 1.f / totx, iy = 1.f / toty;
    float cx = 0.f, cy = 0.f;
    for (int b2 = 0; b2 < NBINS; ++b2) {
      cx += s.hx[b2] * ix; cy += s.hy[b2] * iy;
      s.hx[b2] = cx; s.hy[b2] = cy;
    }
  }
  __syncthreads();
  float p = 0.f;
  if (tid < NBINS) { float d = s.hx[tid] - s.hy[tid]; p = d * d; }
  return blockReduce<0>(p, s.red, tid);  // caller divides by B*BINS
}

// ---------------- db4 wavelet map (writes fm[5][1024], zero-padded) ----------------
__device__ void wavelet_map(const float* row1024, float* fm, SmemFused& s, int tid, bool doEnergy) {
  const float LOF[8] = {-0.010597401784997278f, 0.032883011666982945f, 0.030841381835986965f,
                        -0.18703481171888114f, -0.02798376941698385f, 0.6308807679295904f,
                        0.7148465705525415f, 0.23037781330885523f};
  const float HIF[8] = {0.23037781330885523f, -0.7148465705525415f, 0.6308807679295904f,
                        0.02798376941698385f, -0.18703481171888114f, -0.030841381835986965f,
                        0.032883011666982945f, 0.010597401784997278f};
  const float* ain = row1024;
  int Lin = 1024;
  for (int lvl = 0; lvl < 5; ++lvl) {
    int Lout = Lin >> 1;
    float* aout = (lvl & 1) ? s.aA : s.aB;
    float d = 0.f, a = 0.f;
    if (tid < Lout) {
#pragma unroll
      for (int kk = 0; kk < 8; ++kk) {
        int idx = 2 * tid + kk - 3;   // stride 2, SAME pad (lo=3)
        float v = (idx >= 0 && idx < Lin) ? ain[idx] : 0.f;
        d = fmaf(v, HIF[kk], d);
        a = fmaf(v, LOF[kk], a);
      }
      aout[tid] = a;
    }
    fm[lvl * 1024 + tid] = (tid < Lout) ? d : 0.f;
    if (doEnergy) {
      float e = (tid < Lout) ? fabsf(d) : 0.f;
      float se = blockReduce<0>(e, s.red, tid);
      if (tid == 0) s.energy[lvl] = se * (1.f / 1024.f);
    }
    __syncthreads();
    ain = aout; Lin = Lout;
  }
}

// ---------------- main fused kernel: 192 blocks x 1024 threads ----------------
__global__ __launch_bounds__(1024)
void mdl_main(const float* __restrict__ pred, const float* __restrict__ tgt,
              float* __restrict__ ws) {
  __shared__ SmemU sm;
  const int blk = blockIdx.x;
  const int tid = threadIdx.x;

  if (blk < 128) {
    // =================== soft-DTW wavefront ===================
    SmemDtw& s = sm.d;
    const int mode = blk >> 6;          // 0: raw, 1: second derivative
    const int b = blk & 63;
    const int T = mode ? TSD : TFULL;
    const float* xr = pred + b * 1024;
    const float* yr = tgt + b * 1024;

    float xv = 0.f;
    if (tid < T) {
      xv       = mode ? (xr[tid + 2] - 2.f * xr[tid + 1] + xr[tid]) : xr[tid];
      s.ys[tid] = mode ? (yr[tid + 2] - 2.f * yr[tid + 1] + yr[tid]) : yr[tid];
    }
    float* bufs = (float*)s.buf;
    for (int i = tid; i < 3 * 1026; i += 1024) bufs[i] = BIGV;
    __syncthreads();
    if (tid == 0) s.buf[0][0] = 0.f;    // R[0,0]
    __syncthreads();

    float prev1 = BIGV;                  // own dm1[i]
    const int iT = tid + 1;              // i index of this thread's cell
    const int wbase = (tid >> 6) << 6;
    const int kmin = wbase + 2;          // wave active band
    const int kmax = wbase + 64 + T;
    float* A = s.buf[0];                 // dm2
    float* B = s.buf[1];                 // dm1
    float* C = s.buf[2];                 // dk
    const int twoT = 2 * T;

    for (int k = 2; k <= twoT; ++k) {
      if (k >= kmin && k <= kmax) {      // whole-wave skip of the ramp
        float av = B[tid];               // dm1[i-1]
        float cv = A[tid];               // dm2[i-1]
        float bv = prev1;                // dm1[i]
        int jm1 = k - iT - 1;            // j-1
        int jidx = min(max(jm1, 0), T - 1);
        float yv = s.ys[jidx];
        float diff = xv - yv;
        float cost = diff * diff;
        float m = fminf(fminf(av, bv), cv);
        float e = __expf((m - av) * 10.f) + __expf((m - bv) * 10.f) + __expf((m - cv) * 10.f);
        float sm3 = m - 0.1f * __logf(e);
        bool valid = (jm1 >= 0) && (jm1 < T) && (iT <= T);
        float dk = valid ? (cost + sm3) : BIGV;
        C[iT] = dk;
        if (tid == 0) C[0] = BIGV;       // boundary R[0,*]
        prev1 = dk;
      }
      __syncthreads();
      float* t0 = A; A = B; B = C; C = t0;
    }
    if (tid == 0) ws[blk] = B[T];        // R[T,T] for this batch
  } else {
    // =================== fused per-batch losses ===================
    SmemFused& s = sm.f;
    const int b = blk - 128;
    const float* xg = pred + b * 1024;
    const float* yg = tgt + b * 1024;
    s.xr[tid] = xg[tid];
    s.yr[tid] = yg[tid];
    __syncthreads();

    // second derivative rows, aliased onto fmp region (overwritten later by wavelet)
    float* sdx = s.fmp;
    float* sdy = s.fmp + 1024;
    float sdxv = 0.f, sdyv = 0.f;
    if (tid < TSD) {
      sdxv = s.xr[tid + 2] - 2.f * s.xr[tid + 1] + s.xr[tid];
      sdyv = s.yr[tid + 2] - 2.f * s.yr[tid + 1] + s.yr[tid];
    }
    sdx[tid] = sdxv;
    sdy[tid] = sdyv;

    // sparsity partials (barriers inside blockReduce make sdx/sdy visible after)
    float spp = blockReduce<0>(fabsf(s.xr[tid]), s.red, tid);
    float spd = blockReduce<0>((tid < TSD) ? fabsf(sdxv) : 0.f, s.red, tid);

    float c1 = cdf_pair(s.xr, s.yr, 1024, s, tid);
    float c2 = cdf_pair(sdx, sdy, TSD, s, tid);

    wavelet_map(s.xr, s.fmp, s, tid, true);
    wavelet_map(s.yr, s.fmt, s, tid, false);

    __syncthreads();
    if (tid == 0) {
      float e0 = s.energy[0], e1 = s.energy[1], e2 = s.energy[2], e3 = s.energy[3], e4 = s.energy[4];
      float e[5] = {e0, e1, e2, e3, e4};
      int peak = 0; float best = e[0];
#pragma unroll
      for (int l = 1; l < 5; ++l) if (e[l] > best) { best = e[l]; peak = l; }
      float tot = 0.f, sel = 0.f;
#pragma unroll
      for (int l = 0; l < 5; ++l) {
        tot += e[l];
        if (l >= peak - 2 && l <= peak + 2) sel += e[l];
      }
      s.energy[7] = 1.f - sel / (tot + 1e-6f);
    }
    __syncthreads();
    float fr = s.energy[7];

    float c3 = cdf_pair(s.fmp, s.fmt, 5120, s, tid);

    if (tid == 0) {
      float* o = ws + 256 + b * 8;
      o[0] = c1; o[1] = c2; o[2] = c3;
      o[3] = fr; o[4] = spp; o[5] = spd;
    }
  }
}

// ---------------- final combine: 1 block x 64 threads ----------------
__global__ void mdl_combine(const float* __restrict__ ws, float* __restrict__ out) {
  const int lane = threadIdx.x;
  float vt = ws[lane];               // dtw time partial (batch=lane)
  float vs = ws[64 + lane];          // dtw sd partial
  const float* p = ws + 256 + lane * 8;
  float c1 = p[0], c2 = p[1], c3 = p[2], fr = p[3], sp = p[4], spd = p[5];
  vt = waveReduceSum(vt);  vs = waveReduceSum(vs);
  c1 = waveReduceSum(c1);  c2 = waveReduceSum(c2);  c3 = waveReduceSum(c3);
  fr = waveReduceSum(fr);  sp = waveReduceSum(sp);  spd = waveReduceSum(spd);
  if (lane == 0) {
    float dtw_t = vt * (1.f / 64.f);
    float dtw_s = vs * (1.f / 64.f);
    float l_time = dtw_t + sp * (1.f / 65536.f) + c1 * (1.f / 4096.f);
    float l_sd   = dtw_s + spd * (1.f / 65408.f) + c2 * (1.f / 4096.f);
    float l_freq = fr * (1.f / 64.f) + c3 * (1.f / 4096.f);
    float total = 1.5f * l_time + 0.8f * l_freq + 1.2f * l_sd;
    out[0] = total; out[1] = l_time; out[2] = l_freq; out[3] = l_sd;
  }
}

extern "C" void kernel_launch(void* const* d_in, const int* in_sizes, int n_in,
                              void* d_out, int out_size, void* d_ws, size_t ws_size,
                              hipStream_t stream) {
  const float* pred = (const float*)d_in[0];
  const float* tgt  = (const float*)d_in[1];
  float* out = (float*)d_out;
  float* ws  = (float*)d_ws;
  mdl_main<<<dim3(192), dim3(1024), 0, stream>>>(pred, tgt, ws);
  mdl_combine<<<dim3(1), dim3(64), 0, stream>>>(ws, out);
}